// Round 9
// baseline (2202.665 us; speedup 1.0000x reference)
//
#include <hip/hip_runtime.h>

#define B_SZ    2
#define LSEQ    2048
#define DMODEL  768
#define DINNER  1536
#define NHEADS  24
#define HD      64
#define CDPH    192
#define CONVDIM 4608
#define DIP     6168
#define MROWS   (B_SZ*LSEQ)   // 4096

typedef float f2 __attribute__((ext_vector_type(2)));
typedef float f32x4 __attribute__((ext_vector_type(4)));
typedef short bf16x8 __attribute__((ext_vector_type(8)));
typedef unsigned short us8 __attribute__((ext_vector_type(8)));

__device__ __forceinline__ float siluf(float x) {
    return x / (1.0f + __expf(-x));
}

// lgkm-only barrier: global prefetches stay in flight across it.
#define WBAR() do { asm volatile("s_waitcnt lgkmcnt(0)" ::: "memory"); \
                    __builtin_amdgcn_s_barrier();                      \
                    asm volatile("" ::: "memory"); } while (0)

// Packed fp32 ops (VOP3P, CDNA): one instruction = 2 scalar FMAs.
__device__ __forceinline__ void pk_fma(f2& d, const f2 a, const f2 b) {
    // d = a*b + d  (per 32-bit half)
    asm("v_pk_fma_f32 %0, %1, %2, %0 op_sel:[0,0,0] op_sel_hi:[1,1,1]"
        : "+v"(d) : "v"(a), "v"(b));
}
__device__ __forceinline__ f2 pk_mul(const f2 a, const f2 b) {
    f2 d;
    asm("v_pk_mul_f32 %0, %1, %2 op_sel:[0,0] op_sel_hi:[1,1]"
        : "=v"(d) : "v"(a), "v"(b));
    return d;
}

// Sum over the 4 g-groups (lane, lane^16, lane^32, lane^48), all lanes get
// the result. Pure VALU (gfx950 permlane swaps), zero LDS round-trips.
__device__ __forceinline__ float redux4(float v) {
    float a = v, b = v;
    asm("v_permlane16_swap_b32 %0, %1" : "+v"(a), "+v"(b));
    const float s = a + b;
    float c = s, d = s;
    asm("v_permlane32_swap_b32 %0, %1" : "+v"(c), "+v"(d));
    return c + d;
}

__device__ __forceinline__ ushort f2bf(float v) {  // RNE f32 -> bf16 bits
    uint u = __float_as_uint(v);
    return (ushort)((u + 0x7FFFu + ((u >> 16) & 1u)) >> 16);
}
__device__ __forceinline__ float bf2f(ushort h) {
    return __uint_as_float(((uint)h) << 16);
}

// Elementwise f32 -> (hi,lo) bf16 planes. n4 = count/4.
__global__ __launch_bounds__(256) void cvt_split(
    const float* __restrict__ in, ushort* __restrict__ hi,
    ushort* __restrict__ lo, int n4)
{
    int i = blockIdx.x * blockDim.x + threadIdx.x;
    const int stride = gridDim.x * blockDim.x;
    for (; i < n4; i += stride) {
        const float4 v = ((const float4*)in)[i];
        ushort4 h, l;
        h.x = f2bf(v.x); l.x = f2bf(v.x - bf2f(h.x));
        h.y = f2bf(v.y); l.y = f2bf(v.y - bf2f(h.y));
        h.z = f2bf(v.z); l.z = f2bf(v.z - bf2f(h.z));
        h.w = f2bf(v.w); l.w = f2bf(v.w - bf2f(h.w));
        ((ushort4*)hi)[i] = h;
        ((ushort4*)lo)[i] = l;
    }
}

// C[m,n] = sum_k A[m,k]*B[n,k], fp32 out, split-bf16 MFMA
// (acc += ah*bh + ah*bl + al*bh; lo*lo dropped).
// MODE 0: A,B f32 converted in-kernel. 1: A f32, B pre-split planes.
// 2: both pre-split. 128x128 tile, BK=32, 4 waves (2x2, 64x64 each).
template<int MODE>
__global__ __launch_bounds__(256) void gemm_nt_split(
    const float* __restrict__ A,
    const ushort* __restrict__ Ahi, const ushort* __restrict__ Alo,
    const float* __restrict__ B_,
    const ushort* __restrict__ Bhi, const ushort* __restrict__ Blo,
    float* __restrict__ C, int M, int N, int K)
{
    __shared__ ushort As_hi[128][56];
    __shared__ ushort As_lo[128][56];
    __shared__ ushort Bs_hi[128][56];
    __shared__ ushort Bs_lo[128][56];

    const int ntn = (N + 127) >> 7;
    const int bm = blockIdx.x / ntn;
    const int bn = blockIdx.x - bm * ntn;
    const int m0 = bm << 7, n0 = bn << 7;
    const int tid = threadIdx.x;
    const int wid = tid >> 6;
    const int l = tid & 63;
    const int wm = wid >> 1, wn = wid & 1;       // 2x2 wave grid
    const int lr = l & 15;                       // fragment row/col lane
    const int kq = l >> 4;                       // k-quarter 0..3

    const int srow = tid >> 1;                   // staging row 0..127
    const int scol = (tid & 1) << 4;             // staging col 0 or 16
    const bool bok = (n0 + srow) < N;

    f32x4 acc[4][4];
#pragma unroll
    for (int i = 0; i < 4; ++i)
#pragma unroll
        for (int j = 0; j < 4; ++j) acc[i][j] = f32x4{0.f, 0.f, 0.f, 0.f};

    const size_t arow = (size_t)(m0 + srow) * K + scol;
    const size_t brow = (size_t)(n0 + srow) * K + scol;

    for (int k0 = 0; k0 < K; k0 += 32) {
        // ---- stage A ----
        us8 ah0, ah1, al0, al1;
        float av[16];
        if constexpr (MODE >= 2) {
            ah0 = *(const us8*)(Ahi + arow + k0);
            ah1 = *(const us8*)(Ahi + arow + k0 + 8);
            al0 = *(const us8*)(Alo + arow + k0);
            al1 = *(const us8*)(Alo + arow + k0 + 8);
        } else {
#pragma unroll
            for (int q = 0; q < 4; ++q) {
                const float4 t = *(const float4*)(A + arow + k0 + q * 4);
                av[q*4+0] = t.x; av[q*4+1] = t.y;
                av[q*4+2] = t.z; av[q*4+3] = t.w;
            }
        }
        // ---- stage B ----
        us8 bh0, bh1, bl0, bl1;
        float bv[16];
        if constexpr (MODE >= 1) {
            bh0 = us8{}; bh1 = us8{}; bl0 = us8{}; bl1 = us8{};
            if (bok) {
                bh0 = *(const us8*)(Bhi + brow + k0);
                bh1 = *(const us8*)(Bhi + brow + k0 + 8);
                bl0 = *(const us8*)(Blo + brow + k0);
                bl1 = *(const us8*)(Blo + brow + k0 + 8);
            }
        } else {
#pragma unroll
            for (int q = 0; q < 4; ++q) {
                float4 t = make_float4(0.f, 0.f, 0.f, 0.f);
                if (bok) t = *(const float4*)(B_ + brow + k0 + q * 4);
                bv[q*4+0] = t.x; bv[q*4+1] = t.y;
                bv[q*4+2] = t.z; bv[q*4+3] = t.w;
            }
        }
        __syncthreads();
        if constexpr (MODE >= 2) {
            *(us8*)&As_hi[srow][scol] = ah0; *(us8*)&As_hi[srow][scol + 8] = ah1;
            *(us8*)&As_lo[srow][scol] = al0; *(us8*)&As_lo[srow][scol + 8] = al1;
        } else {
#pragma unroll
            for (int q = 0; q < 16; ++q) {
                const ushort ah = f2bf(av[q]);
                As_hi[srow][scol + q] = ah;
                As_lo[srow][scol + q] = f2bf(av[q] - bf2f(ah));
            }
        }
        if constexpr (MODE >= 1) {
            *(us8*)&Bs_hi[srow][scol] = bh0; *(us8*)&Bs_hi[srow][scol + 8] = bh1;
            *(us8*)&Bs_lo[srow][scol] = bl0; *(us8*)&Bs_lo[srow][scol + 8] = bl1;
        } else {
#pragma unroll
            for (int q = 0; q < 16; ++q) {
                const ushort bh = f2bf(bv[q]);
                Bs_hi[srow][scol + q] = bh;
                Bs_lo[srow][scol + q] = f2bf(bv[q] - bf2f(bh));
            }
        }
        __syncthreads();

        bf16x8 ahf[4], alf[4], bhf[4], blf[4];
#pragma unroll
        for (int f = 0; f < 4; ++f) {
            const int ra = wm * 64 + f * 16 + lr;
            ahf[f] = *(const bf16x8*)&As_hi[ra][kq * 8];
            alf[f] = *(const bf16x8*)&As_lo[ra][kq * 8];
            const int rb = wn * 64 + f * 16 + lr;
            bhf[f] = *(const bf16x8*)&Bs_hi[rb][kq * 8];
            blf[f] = *(const bf16x8*)&Bs_lo[rb][kq * 8];
        }
#pragma unroll
        for (int i = 0; i < 4; ++i)
#pragma unroll
            for (int j = 0; j < 4; ++j) {
                acc[i][j] = __builtin_amdgcn_mfma_f32_16x16x32_bf16(
                    ahf[i], bhf[j], acc[i][j], 0, 0, 0);
                acc[i][j] = __builtin_amdgcn_mfma_f32_16x16x32_bf16(
                    ahf[i], blf[j], acc[i][j], 0, 0, 0);
                acc[i][j] = __builtin_amdgcn_mfma_f32_16x16x32_bf16(
                    alf[i], bhf[j], acc[i][j], 0, 0, 0);
            }
    }

    // C/D layout (guide m89): col = lane&15, row = (lane>>4)*4 + reg
#pragma unroll
    for (int i = 0; i < 4; ++i) {
#pragma unroll
        for (int j = 0; j < 4; ++j) {
            const int n = n0 + wn * 64 + j * 16 + lr;
            if (n < N) {
#pragma unroll
                for (int rg = 0; rg < 4; ++rg) {
                    const int m = m0 + wm * 64 + i * 16 + kq * 4 + rg;
                    C[(size_t)m * N + n] = acc[i][j][rg];
                }
            }
        }
    }
}

// 4-wave scan, 1 chain per block, 2 lgkm barriers/step, permlane reduces,
// packed-fp32 VALU. Lane (w, g=l>>4, r=l&15): owns row p=16*w+r and state
// cols [16g,16g+16).
__global__ __launch_bounds__(256, 1) void mamba_scan8(
    const float* __restrict__ zx,      // [4096, DIP]
    const float* __restrict__ conv_w,  // [4608, 4]
    const float* __restrict__ conv_b,  // [4608]
    const float* __restrict__ R_x,     // [24,64,64]
    const float* __restrict__ R_B,
    const float* __restrict__ R_C,
    const float* __restrict__ R_dt,    // [24,64]
    const float* __restrict__ dt_bias, // [24]
    const float* __restrict__ A_log,   // [24]
    const float* __restrict__ Dvec,    // [24,64]
    float* __restrict__ yz)            // [4096, 1536]
{
    const int b = blockIdx.x / NHEADS;
    const int h = blockIdx.x % NHEADS;
    const int tid = threadIdx.x;
    const int w = tid >> 6;
    const int l = tid & 63;
    const int g = l >> 4;
    const int r = l & 15;
    const int p = (w << 4) + r;   // owned output row 0..63

    __shared__ __attribute__((aligned(16))) float ybuf[64];
    __shared__ __attribute__((aligned(16))) float Bml[64];
    __shared__ __attribute__((aligned(16))) float Cml[64];

    // R row-segments (row p, K-slice [16g,16g+16)) in registers
    f2 Rx2[8], Rb2[8], Rc2[8], Rd2[8];
    {
        const size_t ro = ((size_t)h * 64 + p) * 64 + (g << 4);
#pragma unroll
        for (int q = 0; q < 4; ++q) {
            const float4 v = *(const float4*)(R_x + ro + q * 4);
            Rx2[q*2] = f2{v.x, v.y}; Rx2[q*2+1] = f2{v.z, v.w};
        }
#pragma unroll
        for (int q = 0; q < 4; ++q) {
            const float4 v = *(const float4*)(R_B + ro + q * 4);
            Rb2[q*2] = f2{v.x, v.y}; Rb2[q*2+1] = f2{v.z, v.w};
        }
#pragma unroll
        for (int q = 0; q < 4; ++q) {
            const float4 v = *(const float4*)(R_C + ro + q * 4);
            Rc2[q*2] = f2{v.x, v.y}; Rc2[q*2+1] = f2{v.z, v.w};
        }
#pragma unroll
        for (int q = 0; q < 4; ++q) {
            const float4 v = *(const float4*)(R_dt + h * 64 + (g << 4) + q * 4);
            Rd2[q*2] = f2{v.x, v.y}; Rd2[q*2+1] = f2{v.z, v.w};
        }
    }
    const float Aval = -__expf(A_log[h]);
    const float bias = dt_bias[h];
    const float Dp   = Dvec[h * 64 + p];

    // conv params for channels p, 64+p, 128+p (g-redundant)
    float wx0, wx1, wx2, wx3, wb0, wb1, wb2, wb3, wc0, wc1, wc2, wc3;
    float cbx, cbB, cbC;
    {
        const float* cw = conv_w + (size_t)h * CDPH * 4;
        const float4 vx = *(const float4*)(cw + (size_t)p * 4);
        const float4 vb = *(const float4*)(cw + (size_t)(64 + p) * 4);
        const float4 vc = *(const float4*)(cw + (size_t)(128 + p) * 4);
        wx0 = vx.x; wx1 = vx.y; wx2 = vx.z; wx3 = vx.w;
        wb0 = vb.x; wb1 = vb.y; wb2 = vb.z; wb3 = vb.w;
        wc0 = vc.x; wc1 = vc.y; wc2 = vc.z; wc3 = vc.w;
        cbx = conv_b[h * CDPH + p];
        cbB = conv_b[h * CDPH + 64 + p];
        cbC = conv_b[h * CDPH + 128 + p];
    }
    float hx0 = 0.f, hx1 = 0.f, hx2 = 0.f;
    float hB0 = 0.f, hB1 = 0.f, hB2 = 0.f;
    float hC0 = 0.f, hC1 = 0.f, hC2 = 0.f;

    const float* xbc = zx + (size_t)b * LSEQ * DIP + DINNER + h * CDPH;
    const float* zb  = zx + (size_t)b * LSEQ * DIP + h * HD;
    const float* dtp = zx + (size_t)b * LSEQ * DIP + DINNER + CONVDIM + h;
    float* yzb = yz + (size_t)b * LSEQ * DINNER + h * HD;

    f2 st2[8];
#pragma unroll
    for (int q = 0; q < 8; ++q) st2[q] = f2{0.f, 0.f};

    if (g == 0) ybuf[p] = 0.f;
    __syncthreads();

    float vx_c = xbc[p], vB_c = xbc[64 + p], vC_c = xbc[128 + p];
    float z_c = zb[p];
    float dtr_c = dtp[0];
    int off = DIP;   // element offset of step t+1

    for (int t = 0; t < LSEQ; ++t) {
        // ---- conv (register history) ----
        const float xcx = fmaf(wx3, vx_c, fmaf(wx2, hx2, fmaf(wx1, hx1, fmaf(wx0, hx0, cbx))));
        const float xcB = fmaf(wb3, vB_c, fmaf(wb2, hB2, fmaf(wb1, hB1, fmaf(wb0, hB0, cbB))));
        const float xcC = fmaf(wc3, vC_c, fmaf(wc2, hC2, fmaf(wc1, hC1, fmaf(wc0, hC0, cbC))));
        hx0 = hx1; hx1 = hx2; hx2 = vx_c;
        hB0 = hB1; hB1 = hB2; hB2 = vB_c;
        hC0 = hC1; hC1 = hC2; hC2 = vC_c;

        // ---- prefetch t+1 (vmcnt-only; never drained by WBAR) ----
        const float vx_n = xbc[off + p];
        const float vB_n = xbc[off + 64 + p];
        const float vC_n = xbc[off + 128 + p];
        const float z_n  = zb[off + p];
        const float dtr_n = dtp[off];
        const float zg = siluf(z_c);   // hoisted

        // ---- phase A: 16-K partial dots for row p (packed fp32) ----
        const float4* yb4 = (const float4*)(ybuf + (g << 4));
        f2 ax2 = {0.f, 0.f}, ab2 = {0.f, 0.f}, ac2 = {0.f, 0.f}, ad2 = {0.f, 0.f};
#pragma unroll
        for (int qq = 0; qq < 4; ++qq) {
            const float4 y4 = yb4[qq];
            const f2 ylo = {y4.x, y4.y}, yhi = {y4.z, y4.w};
            pk_fma(ax2, Rx2[qq*2], ylo); pk_fma(ax2, Rx2[qq*2+1], yhi);
            pk_fma(ab2, Rb2[qq*2], ylo); pk_fma(ab2, Rb2[qq*2+1], yhi);
            pk_fma(ac2, Rc2[qq*2], ylo); pk_fma(ac2, Rc2[qq*2+1], yhi);
            pk_fma(ad2, Rd2[qq*2], ylo); pk_fma(ad2, Rd2[qq*2+1], yhi);
        }
        const float ax = ax2.x + ax2.y, ab = ab2.x + ab2.y;
        const float ac = ac2.x + ac2.y, ad = ad2.x + ad2.y;

        // ---- reduce B,C (pure VALU); publish ----
        const float Bm = siluf(xcB + redux4(ab));
        const float Cm = siluf(xcC + redux4(ac));
        if (g == 0) { Bml[p] = Bm; Cml[p] = Cm; }
        WBAR();  // 1

        // ---- issue B/C window reads; overlap x/dt reduce + dt chain ----
        const float4* bm4 = (const float4*)(Bml + (g << 4));
        const float4* cm4 = (const float4*)(Cml + (g << 4));
        const float4 bA = bm4[0], bB = bm4[1], bC = bm4[2], bD = bm4[3];
        const float4 cA = cm4[0], cB = cm4[1], cC = cm4[2], cD = cm4[3];

        const float xv = siluf(xcx + redux4(ax));
        const float dv = dtr_c + redux4(ad) + bias;
        const float dtv = (dv > 15.f) ? dv : __logf(1.f + __expf(dv));
        const float dAv = __expf(dtv * Aval);
        const float kx = dtv * xv;

        // ---- phase B: state update + y partial (packed fp32) ----
        const f2 dA2 = {dAv, dAv};
        const f2 kx2 = {kx, kx};
        f2 bmv[8], cmv[8];
        bmv[0] = f2{bA.x, bA.y}; bmv[1] = f2{bA.z, bA.w};
        bmv[2] = f2{bB.x, bB.y}; bmv[3] = f2{bB.z, bB.w};
        bmv[4] = f2{bC.x, bC.y}; bmv[5] = f2{bC.z, bC.w};
        bmv[6] = f2{bD.x, bD.y}; bmv[7] = f2{bD.z, bD.w};
        cmv[0] = f2{cA.x, cA.y}; cmv[1] = f2{cA.z, cA.w};
        cmv[2] = f2{cB.x, cB.y}; cmv[3] = f2{cB.z, cB.w};
        cmv[4] = f2{cC.x, cC.y}; cmv[5] = f2{cC.z, cC.w};
        cmv[6] = f2{cD.x, cD.y}; cmv[7] = f2{cD.z, cD.w};
        f2 yp2 = {0.f, 0.f};
#pragma unroll
        for (int q = 0; q < 8; ++q) {
            f2 rr = pk_mul(kx2, bmv[q]);   // kx*Bm
            pk_fma(rr, st2[q], dA2);       // + st*dA
            st2[q] = rr;
            pk_fma(yp2, st2[q], cmv[q]);   // y partial
        }
        const float ynew = redux4(yp2.x + yp2.y) + Dp * xv;

        if (g == 0) {
            ybuf[p] = ynew;                              // next step's y_prev
            yzb[p] = ynew * zg;                          // gated output
        }
        WBAR();  // 2

        vx_c = vx_n; vB_c = vB_n; vC_c = vC_n; z_c = z_n; dtr_c = dtr_n;
        off += DIP;
        yzb += DINNER;
    }
}

extern "C" void kernel_launch(void* const* d_in, const int* in_sizes, int n_in,
                              void* d_out, int out_size, void* d_ws, size_t ws_size,
                              hipStream_t stream) {
    const float* u       = (const float*)d_in[0];
    const float* W_in    = (const float*)d_in[1];
    const float* conv_w  = (const float*)d_in[2];
    const float* conv_b  = (const float*)d_in[3];
    const float* R_x     = (const float*)d_in[4];
    const float* R_B     = (const float*)d_in[5];
    const float* R_C     = (const float*)d_in[6];
    const float* R_dt    = (const float*)d_in[7];
    const float* dt_bias = (const float*)d_in[8];
    const float* A_log   = (const float*)d_in[9];
    const float* Dv      = (const float*)d_in[10];
    const float* W_out   = (const float*)d_in[11];
    float* out = (float*)d_out;

    const size_t ZXF = (size_t)MROWS * DIP;       // 25,264,128 floats
    const size_t YZF = (size_t)MROWS * DINNER;    //  6,291,456 floats
    const size_t UE  = (size_t)MROWS * DMODEL;    // u elems
    const size_t WIE = (size_t)DIP * DMODEL;      // W_in elems
    const size_t WOE = (size_t)DMODEL * DINNER;   // W_out elems
    const size_t PLANESF = (UE + WIE + WOE);      // floats for 2 ushort planes
    const size_t NEEDF = ZXF + YZF + PLANESF;

    float* zx = (float*)d_ws;                     // [4096, 6168]
    float* yz = zx + ZXF;                         // [4096, 1536]
    const bool pre = ws_size >= NEEDF * sizeof(float);

    ushort *uhi = nullptr, *ulo = nullptr, *wihi = nullptr, *wilo = nullptr,
           *wohi = nullptr, *wolo = nullptr;
    if (pre) {
        float* pb = yz + YZF;
        uhi  = (ushort*)pb;            ulo  = uhi + UE;
        wihi = (ushort*)(pb + UE);     wilo = wihi + WIE;
        wohi = (ushort*)(pb + UE + WIE); wolo = wohi + WOE;
        cvt_split<<<512, 256, 0, stream>>>(u, uhi, ulo, (int)(UE / 4));
        cvt_split<<<512, 256, 0, stream>>>(W_in, wihi, wilo, (int)(WIE / 4));
        cvt_split<<<512, 256, 0, stream>>>(W_out, wohi, wolo, (int)(WOE / 4));
    }

    {   // in-projection: 4096 x 6168 x 768
        const int M = MROWS, N = DIP, K = DMODEL;
        const int grid = (M / 128) * ((N + 127) / 128);
        if (pre)
            gemm_nt_split<2><<<grid, 256, 0, stream>>>(
                nullptr, uhi, ulo, nullptr, wihi, wilo, zx, M, N, K);
        else
            gemm_nt_split<0><<<grid, 256, 0, stream>>>(
                u, nullptr, nullptr, W_in, nullptr, nullptr, zx, M, N, K);
    }
    mamba_scan8<<<B_SZ * NHEADS, 256, 0, stream>>>(
        zx, conv_w, conv_b, R_x, R_B, R_C, R_dt, dt_bias, A_log, Dv, yz);
    {   // out-projection: 4096 x 768 x 1536 (A=yz converted in-kernel)
        const int M = MROWS, N = DMODEL, K = DINNER;
        const int grid = (M / 128) * ((N + 127) / 128);
        if (pre)
            gemm_nt_split<1><<<grid, 256, 0, stream>>>(
                yz, nullptr, nullptr, nullptr, wohi, wolo, out, M, N, K);
        else
            gemm_nt_split<0><<<grid, 256, 0, stream>>>(
                yz, nullptr, nullptr, W_out, nullptr, nullptr, out, M, N, K);
    }
}

// Round 11
// 1970.290 us; speedup vs baseline: 1.1179x; 1.1179x over previous
//
#include <hip/hip_runtime.h>

#define B_SZ    2
#define LSEQ    2048
#define DMODEL  768
#define DINNER  1536
#define NHEADS  24
#define HD      64
#define CDPH    192
#define CONVDIM 4608
#define DIP     6168
#define MROWS   (B_SZ*LSEQ)   // 4096

typedef float f2 __attribute__((ext_vector_type(2)));
typedef float f32x4 __attribute__((ext_vector_type(4)));
typedef short bf16x8 __attribute__((ext_vector_type(8)));
typedef unsigned short us8 __attribute__((ext_vector_type(8)));

__device__ __forceinline__ float siluf(float x) {
    return x / (1.0f + __expf(-x));
}

// lgkm-only barrier: global prefetches stay in flight across it.
#define WBAR() do { asm volatile("s_waitcnt lgkmcnt(0)" ::: "memory"); \
                    __builtin_amdgcn_s_barrier();                      \
                    asm volatile("" ::: "memory"); } while (0)

// Sum over the 4 g-groups (lane, lane^16, lane^32, lane^48), all lanes get
// the result. Pure VALU (gfx950 permlane swaps), zero LDS round-trips.
__device__ __forceinline__ float redux4(float v) {
    float a = v, b = v;
    asm("v_permlane16_swap_b32 %0, %1" : "+v"(a), "+v"(b));
    const float s = a + b;
    float c = s, d = s;
    asm("v_permlane32_swap_b32 %0, %1" : "+v"(c), "+v"(d));
    return c + d;
}

__device__ __forceinline__ ushort f2bf(float v) {  // RNE f32 -> bf16 bits
    uint u = __float_as_uint(v);
    return (ushort)((u + 0x7FFFu + ((u >> 16) & 1u)) >> 16);
}
__device__ __forceinline__ float bf2f(ushort h) {
    return __uint_as_float(((uint)h) << 16);
}

// Elementwise f32 -> (hi,lo) bf16 planes. n4 = count/4.
__global__ __launch_bounds__(256) void cvt_split(
    const float* __restrict__ in, ushort* __restrict__ hi,
    ushort* __restrict__ lo, int n4)
{
    int i = blockIdx.x * blockDim.x + threadIdx.x;
    const int stride = gridDim.x * blockDim.x;
    for (; i < n4; i += stride) {
        const float4 v = ((const float4*)in)[i];
        ushort4 h, l;
        h.x = f2bf(v.x); l.x = f2bf(v.x - bf2f(h.x));
        h.y = f2bf(v.y); l.y = f2bf(v.y - bf2f(h.y));
        h.z = f2bf(v.z); l.z = f2bf(v.z - bf2f(h.z));
        h.w = f2bf(v.w); l.w = f2bf(v.w - bf2f(h.w));
        ((ushort4*)hi)[i] = h;
        ((ushort4*)lo)[i] = l;
    }
}

// C[m,n] = sum_k A[m,k]*B[n,k], fp32 out, split-bf16 MFMA
// (acc += ah*bh + ah*bl + al*bh; lo*lo dropped).
// MODE 0: A,B f32 converted in-kernel. 1: A f32, B pre-split planes.
// 2: both pre-split. 128x128 tile, BK=32, 4 waves (2x2, 64x64 each).
template<int MODE>
__global__ __launch_bounds__(256) void gemm_nt_split(
    const float* __restrict__ A,
    const ushort* __restrict__ Ahi, const ushort* __restrict__ Alo,
    const float* __restrict__ B_,
    const ushort* __restrict__ Bhi, const ushort* __restrict__ Blo,
    float* __restrict__ C, int M, int N, int K)
{
    __shared__ ushort As_hi[128][56];
    __shared__ ushort As_lo[128][56];
    __shared__ ushort Bs_hi[128][56];
    __shared__ ushort Bs_lo[128][56];

    const int ntn = (N + 127) >> 7;
    const int bm = blockIdx.x / ntn;
    const int bn = blockIdx.x - bm * ntn;
    const int m0 = bm << 7, n0 = bn << 7;
    const int tid = threadIdx.x;
    const int wid = tid >> 6;
    const int l = tid & 63;
    const int wm = wid >> 1, wn = wid & 1;       // 2x2 wave grid
    const int lr = l & 15;                       // fragment row/col lane
    const int kq = l >> 4;                       // k-quarter 0..3

    const int srow = tid >> 1;                   // staging row 0..127
    const int scol = (tid & 1) << 4;             // staging col 0 or 16
    const bool bok = (n0 + srow) < N;

    f32x4 acc[4][4];
#pragma unroll
    for (int i = 0; i < 4; ++i)
#pragma unroll
        for (int j = 0; j < 4; ++j) acc[i][j] = f32x4{0.f, 0.f, 0.f, 0.f};

    const size_t arow = (size_t)(m0 + srow) * K + scol;
    const size_t brow = (size_t)(n0 + srow) * K + scol;

    for (int k0 = 0; k0 < K; k0 += 32) {
        // ---- stage A ----
        us8 ah0, ah1, al0, al1;
        float av[16];
        if constexpr (MODE >= 2) {
            ah0 = *(const us8*)(Ahi + arow + k0);
            ah1 = *(const us8*)(Ahi + arow + k0 + 8);
            al0 = *(const us8*)(Alo + arow + k0);
            al1 = *(const us8*)(Alo + arow + k0 + 8);
        } else {
#pragma unroll
            for (int q = 0; q < 4; ++q) {
                const float4 t = *(const float4*)(A + arow + k0 + q * 4);
                av[q*4+0] = t.x; av[q*4+1] = t.y;
                av[q*4+2] = t.z; av[q*4+3] = t.w;
            }
        }
        // ---- stage B ----
        us8 bh0, bh1, bl0, bl1;
        float bv[16];
        if constexpr (MODE >= 1) {
            bh0 = us8{}; bh1 = us8{}; bl0 = us8{}; bl1 = us8{};
            if (bok) {
                bh0 = *(const us8*)(Bhi + brow + k0);
                bh1 = *(const us8*)(Bhi + brow + k0 + 8);
                bl0 = *(const us8*)(Blo + brow + k0);
                bl1 = *(const us8*)(Blo + brow + k0 + 8);
            }
        } else {
#pragma unroll
            for (int q = 0; q < 4; ++q) {
                float4 t = make_float4(0.f, 0.f, 0.f, 0.f);
                if (bok) t = *(const float4*)(B_ + brow + k0 + q * 4);
                bv[q*4+0] = t.x; bv[q*4+1] = t.y;
                bv[q*4+2] = t.z; bv[q*4+3] = t.w;
            }
        }
        __syncthreads();
        if constexpr (MODE >= 2) {
            *(us8*)&As_hi[srow][scol] = ah0; *(us8*)&As_hi[srow][scol + 8] = ah1;
            *(us8*)&As_lo[srow][scol] = al0; *(us8*)&As_lo[srow][scol + 8] = al1;
        } else {
#pragma unroll
            for (int q = 0; q < 16; ++q) {
                const ushort ah = f2bf(av[q]);
                As_hi[srow][scol + q] = ah;
                As_lo[srow][scol + q] = f2bf(av[q] - bf2f(ah));
            }
        }
        if constexpr (MODE >= 1) {
            *(us8*)&Bs_hi[srow][scol] = bh0; *(us8*)&Bs_hi[srow][scol + 8] = bh1;
            *(us8*)&Bs_lo[srow][scol] = bl0; *(us8*)&Bs_lo[srow][scol + 8] = bl1;
        } else {
#pragma unroll
            for (int q = 0; q < 16; ++q) {
                const ushort bh = f2bf(bv[q]);
                Bs_hi[srow][scol + q] = bh;
                Bs_lo[srow][scol + q] = f2bf(bv[q] - bf2f(bh));
            }
        }
        __syncthreads();

        bf16x8 ahf[4], alf[4], bhf[4], blf[4];
#pragma unroll
        for (int f = 0; f < 4; ++f) {
            const int ra = wm * 64 + f * 16 + lr;
            ahf[f] = *(const bf16x8*)&As_hi[ra][kq * 8];
            alf[f] = *(const bf16x8*)&As_lo[ra][kq * 8];
            const int rb = wn * 64 + f * 16 + lr;
            bhf[f] = *(const bf16x8*)&Bs_hi[rb][kq * 8];
            blf[f] = *(const bf16x8*)&Bs_lo[rb][kq * 8];
        }
#pragma unroll
        for (int i = 0; i < 4; ++i)
#pragma unroll
            for (int j = 0; j < 4; ++j) {
                acc[i][j] = __builtin_amdgcn_mfma_f32_16x16x32_bf16(
                    ahf[i], bhf[j], acc[i][j], 0, 0, 0);
                acc[i][j] = __builtin_amdgcn_mfma_f32_16x16x32_bf16(
                    ahf[i], blf[j], acc[i][j], 0, 0, 0);
                acc[i][j] = __builtin_amdgcn_mfma_f32_16x16x32_bf16(
                    alf[i], bhf[j], acc[i][j], 0, 0, 0);
            }
    }

    // C/D layout (guide m89): col = lane&15, row = (lane>>4)*4 + reg
#pragma unroll
    for (int i = 0; i < 4; ++i) {
#pragma unroll
        for (int j = 0; j < 4; ++j) {
            const int n = n0 + wn * 64 + j * 16 + lr;
            if (n < N) {
#pragma unroll
                for (int rg = 0; rg < 4; ++rg) {
                    const int m = m0 + wm * 64 + i * 16 + kq * 4 + rg;
                    C[(size_t)m * N + n] = acc[i][j][rg];
                }
            }
        }
    }
}

// 4-wave scan (R8-proven body), 1 chain per block, 2 lgkm barriers/step,
// permlane reduces. Lane (w, g=l>>4, r=l&15): owns row p=16*w+r and state
// cols [16g,16g+16). WP=1: write gated output directly as hi/lo bf16 planes
// (bitwise-identical inputs to the out-proj MFMA as the f32+convert path).
template<int WP>
__global__ __launch_bounds__(256, 1) void mamba_scanA(
    const float* __restrict__ zx,      // [4096, DIP]
    const float* __restrict__ conv_w,  // [4608, 4]
    const float* __restrict__ conv_b,  // [4608]
    const float* __restrict__ R_x,     // [24,64,64]
    const float* __restrict__ R_B,
    const float* __restrict__ R_C,
    const float* __restrict__ R_dt,    // [24,64]
    const float* __restrict__ dt_bias, // [24]
    const float* __restrict__ A_log,   // [24]
    const float* __restrict__ Dvec,    // [24,64]
    float* __restrict__ yz,            // [4096, 1536] f32 (WP=0)
    ushort* __restrict__ yzhi,         // [4096, 1536] planes (WP=1)
    ushort* __restrict__ yzlo)
{
    const int b = blockIdx.x / NHEADS;
    const int h = blockIdx.x % NHEADS;
    const int tid = threadIdx.x;
    const int w = tid >> 6;
    const int l = tid & 63;
    const int g = l >> 4;
    const int r = l & 15;
    const int p = (w << 4) + r;   // owned output row 0..63

    __shared__ __attribute__((aligned(16))) float ybuf[64];
    __shared__ __attribute__((aligned(16))) float Bml[64];
    __shared__ __attribute__((aligned(16))) float Cml[64];

    // R row-segments (row p, K-slice [16g,16g+16)) in registers
    f2 Rx2[8], Rb2[8], Rc2[8], Rd2[8];
    {
        const size_t ro = ((size_t)h * 64 + p) * 64 + (g << 4);
#pragma unroll
        for (int q = 0; q < 4; ++q) {
            const float4 v = *(const float4*)(R_x + ro + q * 4);
            Rx2[q*2] = f2{v.x, v.y}; Rx2[q*2+1] = f2{v.z, v.w};
        }
#pragma unroll
        for (int q = 0; q < 4; ++q) {
            const float4 v = *(const float4*)(R_B + ro + q * 4);
            Rb2[q*2] = f2{v.x, v.y}; Rb2[q*2+1] = f2{v.z, v.w};
        }
#pragma unroll
        for (int q = 0; q < 4; ++q) {
            const float4 v = *(const float4*)(R_C + ro + q * 4);
            Rc2[q*2] = f2{v.x, v.y}; Rc2[q*2+1] = f2{v.z, v.w};
        }
#pragma unroll
        for (int q = 0; q < 4; ++q) {
            const float4 v = *(const float4*)(R_dt + h * 64 + (g << 4) + q * 4);
            Rd2[q*2] = f2{v.x, v.y}; Rd2[q*2+1] = f2{v.z, v.w};
        }
    }
    const float Aval = -__expf(A_log[h]);
    const float bias = dt_bias[h];
    const float Dp   = Dvec[h * 64 + p];

    // conv params for channels p, 64+p, 128+p (g-redundant)
    float wx0, wx1, wx2, wx3, wb0, wb1, wb2, wb3, wc0, wc1, wc2, wc3;
    float cbx, cbB, cbC;
    {
        const float* cw = conv_w + (size_t)h * CDPH * 4;
        const float4 vx = *(const float4*)(cw + (size_t)p * 4);
        const float4 vb = *(const float4*)(cw + (size_t)(64 + p) * 4);
        const float4 vc = *(const float4*)(cw + (size_t)(128 + p) * 4);
        wx0 = vx.x; wx1 = vx.y; wx2 = vx.z; wx3 = vx.w;
        wb0 = vb.x; wb1 = vb.y; wb2 = vb.z; wb3 = vb.w;
        wc0 = vc.x; wc1 = vc.y; wc2 = vc.z; wc3 = vc.w;
        cbx = conv_b[h * CDPH + p];
        cbB = conv_b[h * CDPH + 64 + p];
        cbC = conv_b[h * CDPH + 128 + p];
    }
    float hx0 = 0.f, hx1 = 0.f, hx2 = 0.f;
    float hB0 = 0.f, hB1 = 0.f, hB2 = 0.f;
    float hC0 = 0.f, hC1 = 0.f, hC2 = 0.f;

    const float* xbc = zx + (size_t)b * LSEQ * DIP + DINNER + h * CDPH;
    const float* zb  = zx + (size_t)b * LSEQ * DIP + h * HD;
    const float* dtp = zx + (size_t)b * LSEQ * DIP + DINNER + CONVDIM + h;
    float*  yzb  = yz   + (size_t)b * LSEQ * DINNER + h * HD;
    ushort* yzhb = yzhi + (size_t)b * LSEQ * DINNER + h * HD;
    ushort* yzlb = yzlo + (size_t)b * LSEQ * DINNER + h * HD;

    f2 st2[8];
#pragma unroll
    for (int q = 0; q < 8; ++q) st2[q] = f2{0.f, 0.f};

    if (g == 0) ybuf[p] = 0.f;
    __syncthreads();

    float vx_c = xbc[p], vB_c = xbc[64 + p], vC_c = xbc[128 + p];
    float z_c = zb[p];
    float dtr_c = dtp[0];
    int off = DIP;   // element offset of step t+1

    for (int t = 0; t < LSEQ; ++t) {
        // ---- conv (register history) ----
        const float xcx = fmaf(wx3, vx_c, fmaf(wx2, hx2, fmaf(wx1, hx1, fmaf(wx0, hx0, cbx))));
        const float xcB = fmaf(wb3, vB_c, fmaf(wb2, hB2, fmaf(wb1, hB1, fmaf(wb0, hB0, cbB))));
        const float xcC = fmaf(wc3, vC_c, fmaf(wc2, hC2, fmaf(wc1, hC1, fmaf(wc0, hC0, cbC))));
        hx0 = hx1; hx1 = hx2; hx2 = vx_c;
        hB0 = hB1; hB1 = hB2; hB2 = vB_c;
        hC0 = hC1; hC1 = hC2; hC2 = vC_c;

        // ---- prefetch t+1 (vmcnt-only; never drained by WBAR) ----
        const float vx_n = xbc[off + p];
        const float vB_n = xbc[off + 64 + p];
        const float vC_n = xbc[off + 128 + p];
        const float z_n  = zb[off + p];
        const float dtr_n = dtp[off];
        const float zg = siluf(z_c);   // hoisted: only depends on z_c

        // ---- phase A: 16-K partial dots for row p ----
        const float4* yb4 = (const float4*)(ybuf + (g << 4));
        f2 ax2 = {0.f, 0.f}, ab2 = {0.f, 0.f}, ac2 = {0.f, 0.f}, ad2 = {0.f, 0.f};
#pragma unroll
        for (int qq = 0; qq < 4; ++qq) {
            const float4 y4 = yb4[qq];
            const f2 ylo = {y4.x, y4.y}, yhi = {y4.z, y4.w};
            ax2 += Rx2[qq*2] * ylo; ax2 += Rx2[qq*2+1] * yhi;
            ab2 += Rb2[qq*2] * ylo; ab2 += Rb2[qq*2+1] * yhi;
            ac2 += Rc2[qq*2] * ylo; ac2 += Rc2[qq*2+1] * yhi;
            ad2 += Rd2[qq*2] * ylo; ad2 += Rd2[qq*2+1] * yhi;
        }
        const float ax = ax2.x + ax2.y, ab = ab2.x + ab2.y;
        const float ac = ac2.x + ac2.y, ad = ad2.x + ad2.y;

        // ---- reduce B,C (pure VALU); publish ----
        const float Bm = siluf(xcB + redux4(ab));
        const float Cm = siluf(xcC + redux4(ac));
        if (g == 0) { Bml[p] = Bm; Cml[p] = Cm; }
        WBAR();  // 1

        // ---- issue B/C window reads; overlap x/dt reduce + dt chain ----
        const float4* bm4 = (const float4*)(Bml + (g << 4));
        const float4* cm4 = (const float4*)(Cml + (g << 4));
        const float4 bA = bm4[0], bB = bm4[1], bC = bm4[2], bD = bm4[3];
        const float4 cA = cm4[0], cB = cm4[1], cC = cm4[2], cD = cm4[3];

        const float xv = siluf(xcx + redux4(ax));
        const float dv = dtr_c + redux4(ad) + bias;
        const float dtv = (dv > 15.f) ? dv : __logf(1.f + __expf(dv));
        const float dAv = __expf(dtv * Aval);
        const float kx = dtv * xv;

        // ---- phase B: state update + y partial over cols [16g,16g+16) ----
        const f2 dA2 = {dAv, dAv};
        const f2 kx2 = {kx, kx};
        f2 bmv[8], cmv[8];
        bmv[0] = f2{bA.x, bA.y}; bmv[1] = f2{bA.z, bA.w};
        bmv[2] = f2{bB.x, bB.y}; bmv[3] = f2{bB.z, bB.w};
        bmv[4] = f2{bC.x, bC.y}; bmv[5] = f2{bC.z, bC.w};
        bmv[6] = f2{bD.x, bD.y}; bmv[7] = f2{bD.z, bD.w};
        cmv[0] = f2{cA.x, cA.y}; cmv[1] = f2{cA.z, cA.w};
        cmv[2] = f2{cB.x, cB.y}; cmv[3] = f2{cB.z, cB.w};
        cmv[4] = f2{cC.x, cC.y}; cmv[5] = f2{cC.z, cC.w};
        cmv[6] = f2{cD.x, cD.y}; cmv[7] = f2{cD.z, cD.w};
        f2 yp2 = {0.f, 0.f};
#pragma unroll
        for (int q = 0; q < 8; ++q) {
            st2[q] = st2[q] * dA2 + kx2 * bmv[q];
            yp2 += st2[q] * cmv[q];
        }
        const float ynew = redux4(yp2.x + yp2.y) + Dp * xv;

        if (g == 0) {
            ybuf[p] = ynew;                              // next step's y_prev
            if constexpr (WP) {
                const float o = ynew * zg;
                const ushort oh = f2bf(o);
                yzhb[p] = oh;
                yzlb[p] = f2bf(o - bf2f(oh));
            } else {
                yzb[p] = ynew * zg;                      // gated output f32
            }
        }
        WBAR();  // 2

        vx_c = vx_n; vB_c = vB_n; vC_c = vC_n; z_c = z_n; dtr_c = dtr_n;
        off += DIP;
        if constexpr (WP) { yzhb += DINNER; yzlb += DINNER; }
        else              { yzb += DINNER; }
    }
}

extern "C" void kernel_launch(void* const* d_in, const int* in_sizes, int n_in,
                              void* d_out, int out_size, void* d_ws, size_t ws_size,
                              hipStream_t stream) {
    const float* u       = (const float*)d_in[0];
    const float* W_in    = (const float*)d_in[1];
    const float* conv_w  = (const float*)d_in[2];
    const float* conv_b  = (const float*)d_in[3];
    const float* R_x     = (const float*)d_in[4];
    const float* R_B     = (const float*)d_in[5];
    const float* R_C     = (const float*)d_in[6];
    const float* R_dt    = (const float*)d_in[7];
    const float* dt_bias = (const float*)d_in[8];
    const float* A_log   = (const float*)d_in[9];
    const float* Dv      = (const float*)d_in[10];
    const float* W_out   = (const float*)d_in[11];
    float* out = (float*)d_out;

    const size_t ZXF = (size_t)MROWS * DIP;       // 25,264,128 floats
    const size_t YZF = (size_t)MROWS * DINNER;    //  6,291,456 elems
    const size_t UE  = (size_t)MROWS * DMODEL;    // u elems
    const size_t WIE = (size_t)DIP * DMODEL;      // W_in elems
    const size_t WOE = (size_t)DMODEL * DINNER;   // W_out elems
    // pre path: zx + {u,Win,Wout} planes + yz planes (no f32 yz needed)
    const size_t NEEDF = ZXF + UE + WIE + WOE + YZF;

    float* zx = (float*)d_ws;                     // [4096, 6168]
    const bool pre = ws_size >= NEEDF * sizeof(float);

    if (pre) {
        float* pb = zx + ZXF;
        ushort* uhi  = (ushort*)pb;              ushort* ulo  = uhi + UE;
        ushort* wihi = (ushort*)(pb + UE);       ushort* wilo = wihi + WIE;
        ushort* wohi = (ushort*)(pb + UE + WIE); ushort* wolo = wohi + WOE;
        ushort* yzhi = (ushort*)(pb + UE + WIE + WOE);
        ushort* yzlo = yzhi + YZF;

        cvt_split<<<512, 256, 0, stream>>>(u, uhi, ulo, (int)(UE / 4));
        cvt_split<<<512, 256, 0, stream>>>(W_in, wihi, wilo, (int)(WIE / 4));
        cvt_split<<<512, 256, 0, stream>>>(W_out, wohi, wolo, (int)(WOE / 4));

        {   // in-projection: 4096 x 6168 x 768, both operands pre-split
            const int M = MROWS, N = DIP, K = DMODEL;
            const int grid = (M / 128) * ((N + 127) / 128);
            gemm_nt_split<2><<<grid, 256, 0, stream>>>(
                nullptr, uhi, ulo, nullptr, wihi, wilo, zx, M, N, K);
        }
        mamba_scanA<1><<<B_SZ * NHEADS, 256, 0, stream>>>(
            zx, conv_w, conv_b, R_x, R_B, R_C, R_dt, dt_bias, A_log, Dv,
            nullptr, yzhi, yzlo);
        {   // out-projection: 4096 x 768 x 1536, both operands pre-split
            const int M = MROWS, N = DMODEL, K = DINNER;
            const int grid = (M / 128) * ((N + 127) / 128);
            gemm_nt_split<2><<<grid, 256, 0, stream>>>(
                nullptr, yzhi, yzlo, nullptr, wohi, wolo, out, M, N, K);
        }
    } else {
        float* yz = zx + ZXF;                     // [4096, 1536] f32
        {   // in-projection (in-kernel conversion fallback)
            const int M = MROWS, N = DIP, K = DMODEL;
            const int grid = (M / 128) * ((N + 127) / 128);
            gemm_nt_split<0><<<grid, 256, 0, stream>>>(
                u, nullptr, nullptr, W_in, nullptr, nullptr, zx, M, N, K);
        }
        mamba_scanA<0><<<B_SZ * NHEADS, 256, 0, stream>>>(
            zx, conv_w, conv_b, R_x, R_B, R_C, R_dt, dt_bias, A_log, Dv,
            yz, nullptr, nullptr);
        {   // out-projection
            const int M = MROWS, N = DMODEL, K = DINNER;
            const int grid = (M / 128) * ((N + 127) / 128);
            gemm_nt_split<0><<<grid, 256, 0, stream>>>(
                yz, nullptr, nullptr, W_out, nullptr, nullptr, out, M, N, K);
        }
    }
}